// Round 2
// 1049.800 us; speedup vs baseline: 1.1560x; 1.1560x over previous
//
#include <hip/hip_runtime.h>
#include <math.h>

#define NT 256
#define G 4

// fp32 problem (validated earlier session). G=4 batches per block: each weight
// chunk is loaded to registers once and feeds G FMAs against LDS-resident
// activations.
//
// This revision (occupancy + bank-conflict pass):
//  - LDS arena aliasing: xbar/partial/ob/hb/mid live inside the X buffer
//    (all first written after X's last read) -> k_parent LDS 68KB -> ~37.5KB
//    -> 4 blocks/CU instead of 2.
//  - X/u rows padded to 132 floats (68 for E=64): rows no longer all start at
//    bank 0 -> scores-phase ds_read conflicts spread over 32 banks.
//  - q/u/sb (block-invariant query-side of each aggregator) precomputed once
//    in k_setup into a __device__ global instead of per-block compute_usb.

enum {
  I_LEAF = 0, I_SUB, I_SAW, I_SAB, I_LAW, I_LAB, I_PAW, I_PAB,
  I_SCLS, I_SWQKV, I_SBQKV, I_SWO, I_SBO, I_SLNG, I_SLNB, I_SW1, I_SB1, I_SW2, I_SB2,
  I_PCLS, I_PWQKV, I_PBQKV, I_PWO, I_PBO, I_PLNG, I_PLNB, I_PW1, I_PB1, I_PW2, I_PB2,
  I_CLFW, I_CLFB
};

struct P {
  const float* in[32];
  float* parent_al;  // ws [B][2][128]
  float* vecs;       // ws [B][3][128]
  float* out;        // [B][2]
};

// per-aggregator precomputed query side: u[4][E] then sb[4] at offset 4*E.
// aggs: 0,1 = sub (E=64); 2..5 = parent 0..3 (E=128)
__device__ float g_usb[6][520];

__device__ __forceinline__ void LD8(const float* p, float* o) {
  float4 a = ((const float4*)p)[0], b = ((const float4*)p)[1];
  o[0] = a.x; o[1] = a.y; o[2] = a.z; o[3] = a.w;
  o[4] = b.x; o[5] = b.y; o[6] = b.z; o[7] = b.w;
}
__device__ __forceinline__ void fma8(float& acc, const float* x, const float* w) {
#pragma unroll
  for (int i = 0; i < 8; ++i) acc += x[i] * w[i];
}
__device__ __forceinline__ float gelu(float v) {
  return 0.5f * v * (1.0f + erff(v * 0.70710678118654752f));
}

// LayerNorm rows in place: buf [G][E]; one wave per row.
template <int E>
__device__ void ln_rows(float* buf, const float* __restrict__ gg, const float* __restrict__ bb) {
  const int w = threadIdx.x >> 6, lane = threadIdx.x & 63;
  for (int g = w; g < G; g += 4) {
    float* row = buf + g * E;
    float s = 0.f, s2 = 0.f;
    for (int e = lane; e < E; e += 64) { float x = row[e]; s += x; s2 += x * x; }
#pragma unroll
    for (int off = 1; off < 64; off <<= 1) {
      s += __shfl_xor(s, off, 64);
      s2 += __shfl_xor(s2, off, 64);
    }
    float m = s / (float)E;
    float inv = 1.0f / sqrtf(s2 / (float)E - m * m + 1e-5f);
    for (int e = lane; e < E; e += 64) row[e] = (row[e] - m) * inv * gg[e] + bb[e];
  }
}

// ============ setup: per-agg q -> u,sb (block-invariant, once) ============
__global__ __launch_bounds__(NT) void k_setup(P p) {
  const int a = blockIdx.x;  // 0..5
  const int tid = threadIdx.x;
  __shared__ float clsb[128];
  __shared__ float qb[128];
  int E;
  const float *Wq, *bq, *cls;
  if (a < 2) {
    E = 64;
    Wq = p.in[I_SWQKV] + (size_t)a * 192 * 64;
    bq = p.in[I_SBQKV] + a * 192;
    cls = p.in[I_SCLS] + a * 64;
  } else {
    E = 128;
    int i = a - 2;
    Wq = p.in[I_PWQKV] + (size_t)i * 384 * 128;
    bq = p.in[I_PBQKV] + i * 384;
    cls = p.in[I_PCLS] + i * 128;
  }
  const int D = E / 4;
  const float scale = (E == 64) ? 0.25f : 0.17677669529663687f;
  if (tid < E) clsb[tid] = cls[tid];
  __syncthreads();
  if (tid < E) {
    float acc = bq[tid];
    const float* w = Wq + (size_t)tid * E;
    for (int k = 0; k < E; k += 8) {
      float wv[8];
      LD8(w + k, wv);
#pragma unroll
      for (int ii = 0; ii < 8; ++ii) acc += clsb[k + ii] * wv[ii];
    }
    qb[tid] = acc;
  }
  __syncthreads();
  if (tid < E) {
    for (int h = 0; h < 4; ++h) {
      float acc = 0.f;
      for (int d = 0; d < D; ++d)
        acc += Wq[(size_t)(E + h * D + d) * E + tid] * qb[h * D + d];
      g_usb[a][h * E + tid] = acc * scale;
    }
  }
  if (tid < 4) {
    float acc = 0.f;
    for (int d = 0; d < D; ++d) acc += qb[tid * D + d] * bq[E + tid * D + d];
    g_usb[a][4 * E + tid] = acc * scale;
  }
}

// Folded CLS-only aggregator over G batches.
// X: fp32 tokens [T*G][XP] (rows 1..S-1 of xc, padded rows). Result in ob.
// xbar/partial/ob/hb/mid may alias X (first written after X's last read).
template <int E, int T, int XP>
__device__ void agg_run(const float* X, const float* clsb,
                        const float* uL, const float* sbL,
                        const float* __restrict__ Wv, const float* __restrict__ bv,
                        const float* __restrict__ Wo, const float* __restrict__ bo,
                        const float* __restrict__ lng, const float* __restrict__ lnb,
                        const float* __restrict__ W1, const float* __restrict__ b1,
                        const float* __restrict__ W2, const float* __restrict__ b2,
                        float* att, float* xbar, float* ob, float* hb, float* mid,
                        float* partial) {
  const int tid = threadIdx.x;
  constexpr int S = T + 1, KS = NT / E, KCH = E / KS;
  constexpr int M1 = (4 * E) / NT, KCH2 = (4 * E) / KS;

  // scores[g][h][s] = sb[h] + x_s . u_h  (u rows padded -> banks spread)
  for (int i = tid; i < G * 4 * S; i += NT) {
    int s = i % S, hh = (i / S) % 4, g = i / (4 * S);
    const float* u = uL + hh * XP;
    const float* x = (s == 0) ? clsb : (X + (size_t)((s - 1) * G + g) * XP);
    float acc = sbL[hh];
    for (int k = 0; k < E; k += 8) {
      float xv[8], uv[8];
      LD8(x + k, xv);
      LD8(u + k, uv);
      fma8(acc, xv, uv);
    }
    att[(g * 4 + hh) * S + s] = acc;
  }
  __syncthreads();
  // softmax over s
  for (int i = tid; i < G * 4; i += NT) {
    float* a = att + i * S;
    float mx = a[0];
    for (int s = 1; s < S; ++s) mx = fmaxf(mx, a[s]);
    float sum = 0.f;
    for (int s = 0; s < S; ++s) { float e = expf(a[s] - mx); a[s] = e; sum += e; }
    float inv = 1.0f / sum;
    for (int s = 0; s < S; ++s) a[s] *= inv;
  }
  __syncthreads();
  // xbar[g][h][k] = sum_s att * x_s[k] -- register-staged so xbar may alias X
  constexpr int NI = (G * 4 * E) / NT;
  float xacc[NI];
#pragma unroll
  for (int n = 0; n < NI; ++n) {
    int i = tid + n * NT;
    int k = i % E, hh = (i / E) % 4, g = i / (4 * E);
    const float* a = att + (g * 4 + hh) * S;
    float acc = a[0] * clsb[k];
    for (int s = 1; s < S; ++s) acc += a[s] * X[(size_t)((s - 1) * G + g) * XP + k];
    xacc[n] = acc;
  }
  __syncthreads();  // all X reads complete; X is dead from here on
#pragma unroll
  for (int n = 0; n < NI; ++n) xbar[tid + n * NT] = xacc[n];
  __syncthreads();
  // o[e] = bv[e] + Wv[e][:] . xbar[head(e)][:]
  {
    const int e = tid % E, ks = tid / E, hh = e / (E / 4);
    const float* w = Wv + (size_t)e * E + ks * KCH;
    float acc[G];
#pragma unroll
    for (int g = 0; g < G; ++g) acc[g] = 0.f;
    for (int kc = 0; kc < KCH; kc += 8) {
      float wv[8];
      LD8(w + kc, wv);
#pragma unroll
      for (int g = 0; g < G; ++g) {
        float xv[8];
        LD8(xbar + (g * 4 + hh) * E + ks * KCH + kc, xv);
        fma8(acc[g], xv, wv);
      }
    }
#pragma unroll
    for (int g = 0; g < G; ++g) partial[(ks * G + g) * E + e] = acc[g];
  }
  __syncthreads();
  for (int i = tid; i < G * E; i += NT) {
    int e = i % E, g = i / E;
    float v = bv[e];
#pragma unroll
    for (int ks = 0; ks < KS; ++ks) v += partial[(ks * G + g) * E + e];
    ob[g * E + e] = v;
  }
  __syncthreads();
  // h[e] = bo[e] + cls[e] + Wo[e][:] . o[:]
  {
    const int e = tid % E, ks = tid / E;
    const float* w = Wo + (size_t)e * E + ks * KCH;
    float acc[G];
#pragma unroll
    for (int g = 0; g < G; ++g) acc[g] = 0.f;
    for (int kc = 0; kc < KCH; kc += 8) {
      float wv[8];
      LD8(w + kc, wv);
#pragma unroll
      for (int g = 0; g < G; ++g) {
        float xv[8];
        LD8(ob + g * E + ks * KCH + kc, xv);
        fma8(acc[g], xv, wv);
      }
    }
#pragma unroll
    for (int g = 0; g < G; ++g) partial[(ks * G + g) * E + e] = acc[g];
  }
  __syncthreads();
  for (int i = tid; i < G * E; i += NT) {
    int e = i % E, g = i / E;
    float v = bo[e] + clsb[e];
#pragma unroll
    for (int ks = 0; ks < KS; ++ks) v += partial[(ks * G + g) * E + e];
    hb[g * E + e] = v;
  }
  __syncthreads();
  ln_rows<E>(hb, lng, lnb);
  __syncthreads();
  // mid[m] = gelu(h @ W1 + b1)[m]
  {
    float acc[M1][G];
#pragma unroll
    for (int r = 0; r < M1; ++r)
#pragma unroll
      for (int g = 0; g < G; ++g) acc[r][g] = 0.f;
    for (int j = 0; j < E; j += 8) {
      float wv[M1][8];
#pragma unroll
      for (int ii = 0; ii < 8; ++ii) {
        if constexpr (M1 == 2) {
          float2 w2 = *(const float2*)(W1 + (size_t)(j + ii) * 4 * E + 2 * tid);
          wv[0][ii] = w2.x;
          wv[1][ii] = w2.y;
        } else {
          wv[0][ii] = W1[(size_t)(j + ii) * 4 * E + tid];
        }
      }
#pragma unroll
      for (int g = 0; g < G; ++g) {
        float xv[8];
        LD8(hb + g * E + j, xv);
#pragma unroll
        for (int r = 0; r < M1; ++r) fma8(acc[r][g], xv, wv[r]);
      }
    }
#pragma unroll
    for (int r = 0; r < M1; ++r) {
      int m = tid * M1 + r;
      float bias = b1[m];
#pragma unroll
      for (int g = 0; g < G; ++g) mid[g * 4 * E + m] = gelu(acc[r][g] + bias);
    }
  }
  __syncthreads();
  // out = LN(h + mid @ W2 + b2) -> ob
  {
    const int e = tid % E, ks = tid / E, m0 = ks * KCH2;
    float acc[G];
#pragma unroll
    for (int g = 0; g < G; ++g) acc[g] = 0.f;
    for (int mc = 0; mc < KCH2; mc += 8) {
      float wv[8];
#pragma unroll
      for (int ii = 0; ii < 8; ++ii) wv[ii] = W2[(size_t)(m0 + mc + ii) * E + e];
#pragma unroll
      for (int g = 0; g < G; ++g) {
        float xv[8];
        LD8(mid + g * 4 * E + m0 + mc, xv);
        fma8(acc[g], xv, wv);
      }
    }
#pragma unroll
    for (int g = 0; g < G; ++g) partial[(ks * G + g) * E + e] = acc[g];
  }
  __syncthreads();
  for (int i = tid; i < G * E; i += NT) {
    int e = i % E, g = i / E;
    float v = b2[e] + hb[g * E + e];
#pragma unroll
    for (int ks = 0; ks < KS; ++ks) v += partial[(ks * G + g) * E + e];
    ob[g * E + e] = v;
  }
  __syncthreads();
  ln_rows<E>(ob, lng, lnb);
  __syncthreads();
}

// ===================== kernel 1: sub path =====================
__global__ __launch_bounds__(NT, 4) void k_sub(P p) {
  constexpr int XP = 68;  // padded row (64 + 4): rows spread over banks
  __shared__ __align__(16) float X1[8 * G * XP];
  __shared__ __align__(16) float X2[3 * G * XP];
  __shared__ __align__(16) float clsb[64];
  __shared__ __align__(16) float uL[4 * XP];
  __shared__ __align__(16) float sbL[4];
  __shared__ __align__(16) float att[G * 4 * 9];
  __shared__ __align__(16) float xbar[G * 4 * 64];
  __shared__ __align__(16) float ob[G * 64];
  __shared__ __align__(16) float hb[G * 64];
  __shared__ __align__(16) float mid[G * 256];
  __shared__ __align__(16) float partial[4 * G * 64];
  __shared__ __align__(16) float vec1[G * 64];
  const int tid = threadIdx.x, b0 = blockIdx.x * G;

  // subfield align straight from global (feature reads are wave-uniform)
  const float* subf = p.in[I_SUB];
  const float* saW = p.in[I_SAW];
  const float* sab = p.in[I_SAB];
  for (int i = tid; i < 11 * 64; i += NT) {
    int f = i / 64, e = i % 64;
    float bias = sab[f * 64 + e];
    float acc[G];
#pragma unroll
    for (int g = 0; g < G; ++g) acc[g] = bias;
    for (int d = 0; d < 32; d += 8) {
      float wv[8];
#pragma unroll
      for (int ii = 0; ii < 8; ++ii) wv[ii] = saW[(size_t)(f * 32 + d + ii) * 64 + e];
#pragma unroll
      for (int g = 0; g < G; ++g) {
        float xv[8];
        LD8(subf + (size_t)(b0 + g) * 352 + f * 32 + d, xv);
        fma8(acc[g], xv, wv);
      }
    }
#pragma unroll
    for (int g = 0; g < G; ++g) {
      if (f < 8) X1[(f * G + g) * XP + e] = acc[g];
      else       X2[((f - 8) * G + g) * XP + e] = acc[g];
    }
  }
  // agg1 query side (precomputed) + cls
  for (int i = tid; i < 4 * 64; i += NT) uL[(i >> 6) * XP + (i & 63)] = g_usb[0][i];
  if (tid < 4) sbL[tid] = g_usb[0][256 + tid];
  if (tid < 64) clsb[tid] = p.in[I_SCLS][tid];
  __syncthreads();

  // agg1: tcp.flags (subfields 0..7)
  agg_run<64, 8, XP>(X1, clsb, uL, sbL,
                     p.in[I_SWQKV] + 2 * 64 * 64, p.in[I_SBQKV] + 128,
                     p.in[I_SWO], p.in[I_SBO], p.in[I_SLNG], p.in[I_SLNB],
                     p.in[I_SW1], p.in[I_SB1], p.in[I_SW2], p.in[I_SB2],
                     att, xbar, ob, hb, mid, partial);
  for (int i = tid; i < G * 64; i += NT) vec1[i] = ob[i];

  // agg2 query side
  for (int i = tid; i < 4 * 64; i += NT) uL[(i >> 6) * XP + (i & 63)] = g_usb[1][i];
  if (tid < 4) sbL[tid] = g_usb[1][256 + tid];
  if (tid < 64) clsb[tid] = p.in[I_SCLS][64 + tid];
  __syncthreads();

  // agg2: ip.flags (subfields 8..10)
  agg_run<64, 3, XP>(X2, clsb, uL, sbL,
                     p.in[I_SWQKV] + 192 * 64 + 2 * 64 * 64, p.in[I_SBQKV] + 192 + 128,
                     p.in[I_SWO] + 64 * 64, p.in[I_SBO] + 64,
                     p.in[I_SLNG] + 64, p.in[I_SLNB] + 64,
                     p.in[I_SW1] + 64 * 256, p.in[I_SB1] + 256,
                     p.in[I_SW2] + 256 * 64, p.in[I_SB2] + 64,
                     att, xbar, ob, hb, mid, partial);

  // parent_al: [:,0] = tcpf @ paW0 + pab0 ; [:,1] = ipf @ paW1 + pab1
  {
    const int pi = tid >> 7, e = tid & 127;
    const float* paW = p.in[I_PAW];
    float bias = p.in[I_PAB][pi * 128 + e];
    float acc[G];
#pragma unroll
    for (int g = 0; g < G; ++g) acc[g] = bias;
    const float* src = pi ? ob : vec1;
    for (int j = 0; j < 64; j += 8) {
      float wv[8];
#pragma unroll
      for (int ii = 0; ii < 8; ++ii) wv[ii] = paW[(size_t)(pi * 64 + j + ii) * 128 + e];
#pragma unroll
      for (int g = 0; g < G; ++g) {
        float xv[8];
        LD8(src + g * 64 + j, xv);
        fma8(acc[g], xv, wv);
      }
    }
#pragma unroll
    for (int g = 0; g < G; ++g)
      p.parent_al[(size_t)(b0 + g) * 256 + pi * 128 + e] = acc[g];
  }
}

// ===================== kernel 2: parent aggs =====================
// arena layout (floats), regions live only after X is dead:
//   xbar 0..2048 | partial 2048..3072 | ob 3072..3584 | hb 3584..4096 | mid 4096..6144
#define PXP 132  // padded parent row (128 + 4)

template <int T, int F, int F0, int PAR, int AI>
__device__ void parent_body(const P& p, int b0, float* arena, float* clsb,
                            float* uL, float* sbL, float* att) {
  const int tid = threadIdx.x;
  float* X = arena;
  const float* leaf = p.in[I_LEAF];
  const float* laW = p.in[I_LAW];
  const float* lab = p.in[I_LAB];
  // leaf align straight from global (feature reads are wave-uniform)
  for (int i = tid; i < F * 128; i += NT) {
    int f = i / 128, e = i % 128;
    float bias = lab[(F0 + f) * 128 + e];
    float acc[G];
#pragma unroll
    for (int g = 0; g < G; ++g) acc[g] = bias;
    for (int d = 0; d < 32; d += 8) {
      float wv[8];
#pragma unroll
      for (int ii = 0; ii < 8; ++ii)
        wv[ii] = laW[(size_t)((F0 + f) * 32 + d + ii) * 128 + e];
#pragma unroll
      for (int g = 0; g < G; ++g) {
        float xv[8];
        LD8(leaf + (size_t)(b0 + g) * 1088 + (F0 + f) * 32 + d, xv);
        fma8(acc[g], xv, wv);
      }
    }
#pragma unroll
    for (int g = 0; g < G; ++g) X[(f * G + g) * PXP + e] = acc[g];
  }
  if constexpr (PAR >= 0) {
    for (int i = tid; i < G * 128; i += NT) {
      int g = i / 128, e = i % 128;
      X[((T - 1) * G + g) * PXP + e] = p.parent_al[(size_t)(b0 + g) * 256 + PAR * 128 + e];
    }
  }
  for (int i = tid; i < 4 * 128; i += NT) uL[(i >> 7) * PXP + (i & 127)] = g_usb[2 + AI][i];
  if (tid < 4) sbL[tid] = g_usb[2 + AI][512 + tid];
  if (tid < 128) clsb[tid] = p.in[I_PCLS][AI * 128 + tid];
  __syncthreads();

  float* xbar = arena;
  float* partial = arena + 2048;
  float* ob = arena + 3072;
  float* hb = arena + 3584;
  float* mid = arena + 4096;
  agg_run<128, T, PXP>(X, clsb, uL, sbL,
                       p.in[I_PWQKV] + (size_t)AI * 384 * 128 + 2 * 128 * 128,
                       p.in[I_PBQKV] + AI * 384 + 256,
                       p.in[I_PWO] + (size_t)AI * 128 * 128, p.in[I_PBO] + AI * 128,
                       p.in[I_PLNG] + AI * 128, p.in[I_PLNB] + AI * 128,
                       p.in[I_PW1] + (size_t)AI * 128 * 512, p.in[I_PB1] + AI * 512,
                       p.in[I_PW2] + (size_t)AI * 512 * 128, p.in[I_PB2] + AI * 128,
                       att, xbar, ob, hb, mid, partial);
  for (int i = tid; i < G * 128; i += NT) {
    int e = i % 128, g = i / 128;
    p.vecs[(size_t)(b0 + g) * 384 + AI * 128 + e] = ob[g * 128 + e];
  }
}

__global__ __launch_bounds__(NT, 4) void k_parent(P p) {
  __shared__ __align__(16) float arena[16 * G * PXP];  // 8448 floats = 33.8KB
  __shared__ __align__(16) float clsb[128];
  __shared__ __align__(16) float uL[4 * PXP];
  __shared__ __align__(16) float sbL[4];
  __shared__ __align__(16) float att[G * 4 * 17];
  const int b0 = blockIdx.x * G;
  if (blockIdx.y == 0)
    parent_body<8, 8, 0, -1, 0>(p, b0, arena, clsb, uL, sbL, att);
  else if (blockIdx.y == 1)
    parent_body<12, 11, 8, 1, 1>(p, b0, arena, clsb, uL, sbL, att);
  else
    parent_body<16, 15, 19, 0, 2>(p, b0, arena, clsb, uL, sbL, att);
}

// ===================== kernel 3: pkt agg + classifier =====================
__global__ __launch_bounds__(NT, 4) void k_pkt(P p) {
  __shared__ __align__(16) float arena[6144];  // X (12 rows) + scratch overlay
  __shared__ __align__(16) float clsb[128];
  __shared__ __align__(16) float uL[4 * PXP];
  __shared__ __align__(16) float sbL[4];
  __shared__ __align__(16) float att[G * 4 * 4];
  const int tid = threadIdx.x, b0 = blockIdx.x * G;
  float* X = arena;

  for (int i = tid; i < 3 * G * 128; i += NT) {
    int e = i % 128, g = (i / 128) % G, t = i / (G * 128);
    X[(t * G + g) * PXP + e] = p.vecs[(size_t)(b0 + g) * 384 + t * 128 + e];
  }
  for (int i = tid; i < 4 * 128; i += NT) uL[(i >> 7) * PXP + (i & 127)] = g_usb[5][i];
  if (tid < 4) sbL[tid] = g_usb[5][512 + tid];
  if (tid < 128) clsb[tid] = p.in[I_PCLS][3 * 128 + tid];
  __syncthreads();

  float* xbar = arena;
  float* partial = arena + 2048;
  float* ob = arena + 3072;
  float* hb = arena + 3584;
  float* mid = arena + 4096;
  agg_run<128, 3, PXP>(X, clsb, uL, sbL,
                       p.in[I_PWQKV] + (size_t)3 * 384 * 128 + 2 * 128 * 128,
                       p.in[I_PBQKV] + 3 * 384 + 256,
                       p.in[I_PWO] + (size_t)3 * 128 * 128, p.in[I_PBO] + 3 * 128,
                       p.in[I_PLNG] + 3 * 128, p.in[I_PLNB] + 3 * 128,
                       p.in[I_PW1] + (size_t)3 * 128 * 512, p.in[I_PB1] + 3 * 512,
                       p.in[I_PW2] + (size_t)3 * 512 * 128, p.in[I_PB2] + 3 * 128,
                       att, xbar, ob, hb, mid, partial);

  if (tid < G * 2) {
    int g = tid >> 1, c = tid & 1;
    const float* cw = p.in[I_CLFW];
    float acc = p.in[I_CLFB][c];
    for (int j = 0; j < 128; ++j) acc += ob[g * 128 + j] * cw[j * 2 + c];
    p.out[(size_t)(b0 + g) * 2 + c] = acc;
  }
}

extern "C" void kernel_launch(void* const* d_in, const int* in_sizes, int n_in,
                              void* d_out, int out_size, void* d_ws, size_t ws_size,
                              hipStream_t stream) {
  P p;
  for (int i = 0; i < 32; ++i) p.in[i] = (const float*)d_in[i];
  const int B = in_sizes[0] / (34 * 32);
  float* ws = (float*)d_ws;
  p.parent_al = ws;                        // B*256 floats
  p.vecs = ws + (size_t)B * 256;           // B*384 floats
  p.out = (float*)d_out;

  k_setup<<<dim3(6), dim3(NT), 0, stream>>>(p);
  k_sub<<<dim3(B / G), dim3(NT), 0, stream>>>(p);
  k_parent<<<dim3(B / G, 3), dim3(NT), 0, stream>>>(p);
  k_pkt<<<dim3(B / G), dim3(NT), 0, stream>>>(p);
}